// Round 3
// baseline (3550.339 us; speedup 1.0000x reference)
//
#include <hip/hip_runtime.h>
#include <hip/hip_bf16.h>

// ---------------- problem shape ----------------
#define TT 64
#define BB 256
#define DD 1024
#define HH 1024
#define G4 4096    // 4*H
#define CHT 16     // xg chunk length (timesteps); 4 chunks cover T=64
#define NBLK_LSTM 128

typedef __bf16 bf16x8 __attribute__((ext_vector_type(8)));
typedef float  f32x4  __attribute__((ext_vector_type(4)));

// ---------------- static device scratch (~119 MB, Round-1-proven size) ----------------
__device__ unsigned short g_seq [(size_t)TT * BB * 1024];  // x (bf16) -> layer-1 h seq   32 MB
__device__ unsigned short g_Wih [(size_t)2 * G4 * 1024];   // 16 MB
__device__ unsigned short g_Whh [(size_t)2 * G4 * 1024];   // 16 MB
__device__ unsigned short g_Wfh [(size_t)2 * G4 * 1024];   // 16 MB
__device__ unsigned short g_feat[(size_t)BB * 1024];       // 0.5 MB
__device__ unsigned short g_xg  [(size_t)CHT * BB * G4];   // bf16 gates chunk            32 MB
__device__ unsigned short g_h   [2][(size_t)BB * HH];      // h state ping-pong (bf16)     1 MB
__device__ float          g_featb[(size_t)BB * G4];        // f32 feat@Wfh^T + b           4 MB
__device__ float          g_c   [(size_t)BB * HH];         // f32 cell state               1 MB

// grid-barrier state (monotonic epoch: safe across graph replays)
__device__ unsigned g_bar_cnt = 0;
__device__ unsigned g_bar_epoch = 0;

__device__ __forceinline__ bf16x8 ld8(const __hip_bfloat16* p) {
    return *reinterpret_cast<const bf16x8*>(p);
}
__device__ __forceinline__ __hip_bfloat16* BP(unsigned short* p) {
    return reinterpret_cast<__hip_bfloat16*>(p);
}
__device__ __forceinline__ const __hip_bfloat16* BPc(const unsigned short* p) {
    return reinterpret_cast<const __hip_bfloat16*>(p);
}
__device__ __forceinline__ f32x4 MF(bf16x8 a, bf16x8 b, f32x4 c) {
    return __builtin_amdgcn_mfma_f32_16x16x32_bf16(a, b, c, 0, 0, 0);
}

// direct global->LDS async copy, 16B per lane
typedef unsigned int u32_g __attribute__((address_space(1)));
typedef unsigned int u32_l __attribute__((address_space(3)));
__device__ __forceinline__ void gload16(const void* g, void* l) {
    __builtin_amdgcn_global_load_lds((const u32_g*)g, (u32_l*)l, 16, 0, 0);
}

// =============================================================
// f32 -> bf16 conversion into a selected device-global buffer.
// =============================================================
__global__ __launch_bounds__(256) void cvt_bf16(int which,
                                                const float* __restrict__ s,
                                                size_t n)
{
    size_t i = ((size_t)blockIdx.x * 256 + threadIdx.x) * 4;
    if (i >= n) return;
    unsigned short* d = (which == 0) ? g_seq
                      : (which == 1) ? g_Wih
                      : (which == 2) ? g_Whh
                      : (which == 3) ? g_Wfh : g_feat;
    float4 v = *reinterpret_cast<const float4*>(s + i);
    __hip_bfloat16* db = BP(d) + i;
    db[0] = __float2bfloat16(v.x);
    db[1] = __float2bfloat16(v.y);
    db[2] = __float2bfloat16(v.z);
    db[3] = __float2bfloat16(v.w);
}

// =============================================================
// Small-M featb GEMM: g_featb[256,4096] = feat @ Wfh[l]^T + b[l] (f32)
// =============================================================
__global__ __launch_bounds__(256) void gemm_featb(size_t w_off,
                                                  const float* __restrict__ bias)
{
    const int tid  = threadIdx.x;
    const int lane = tid & 63, wid = tid >> 6;
    const int row  = lane & 15, quad = lane >> 4;
    const int m_base = blockIdx.y * 128 + (wid >> 1) * 64;
    const int n_base = blockIdx.x * 64  + (wid & 1) * 32;

    const __hip_bfloat16* A = BPc(g_feat);
    const __hip_bfloat16* W = BPc(g_Wfh) + w_off;

    f32x4 acc[4][2] = {};
    const __hip_bfloat16* Ap = A + (size_t)(m_base + row) * 1024 + quad * 8;
    const __hip_bfloat16* Wp = W + (size_t)(n_base + row) * 1024 + quad * 8;

    for (int k0 = 0; k0 < 1024; k0 += 32) {
        bf16x8 a[4], b[2];
#pragma unroll
        for (int i = 0; i < 4; ++i) a[i] = ld8(Ap + (size_t)(16 * i) * 1024 + k0);
#pragma unroll
        for (int j = 0; j < 2; ++j) b[j] = ld8(Wp + (size_t)(16 * j) * 1024 + k0);
#pragma unroll
        for (int i = 0; i < 4; ++i)
#pragma unroll
            for (int j = 0; j < 2; ++j)
                acc[i][j] = MF(a[i], b[j], acc[i][j]);
    }
#pragma unroll
    for (int i = 0; i < 4; ++i)
#pragma unroll
        for (int j = 0; j < 2; ++j) {
            const int n = n_base + 16 * j + row;
#pragma unroll
            for (int r = 0; r < 4; ++r) {
                const int m = m_base + 16 * i + quad * 4 + r;
                g_featb[(size_t)m * G4 + n] = acc[i][j][r] + bias[n];
            }
        }
}

// =============================================================
// xg GEMM (chunk): C[4096,4096] = g_seq[chunk] @ Wih[l]^T  (+featb, ->bf16)
// 128x128 tile, BK=32, double-buffered LDS via global_load_lds(16B).
// Bank-conflict fix (rule #21, both-sides involution): LDS dest LINEAR,
// global source pre-permuted by s' = s ^ ((s>>3)&7) on 16B-granules,
// ds_read applies the same involution -> each 8-lane phase covers all 8
// bank-groups (was 4-way: 4.19M SQ_LDS_BANK_CONFLICT/dispatch).
// =============================================================
__global__ __launch_bounds__(256) void gemm_xg(size_t seq_off, size_t w_off)
{
    __shared__ unsigned short lA[2][128 * 32];
    __shared__ unsigned short lB[2][128 * 32];

    const int tid  = threadIdx.x;
    const int lane = tid & 63, wv = tid >> 6;
    const int row  = lane & 15, quad = lane >> 4;
    const int wr = wv >> 1, wc = wv & 1;
    const int m_base = blockIdx.y * 128;
    const int n_base = blockIdx.x * 128;

    const __hip_bfloat16* A  = BPc(g_seq) + seq_off + (size_t)m_base * 1024;
    const __hip_bfloat16* Wt = BPc(g_Wih) + w_off   + (size_t)n_base * 1024;

    f32x4 acc[4][4] = {};

    const int sm = (tid >> 3) & 7;                   // == (d>>3)&7 for d=it*256+tid
    auto STAGE = [&](int bf, int kt) {
        const int k0 = kt * 32;
#pragma unroll
        for (int it = 0; it < 2; ++it) {
            const int d = it * 256 + tid;
            const int l = d ^ sm;                    // involutive granule permutation
            const int r  = l >> 2;
            const int kc = k0 + (l & 3) * 8;
            unsigned short* dA = &lA[bf][(size_t)(it * 256 + wv * 64) * 8];
            unsigned short* dB = &lB[bf][(size_t)(it * 256 + wv * 64) * 8];
            gload16(A  + (size_t)r * 1024 + kc, dA);
            gload16(Wt + (size_t)r * 1024 + kc, dB);
        }
    };

    STAGE(0, 0);
    asm volatile("s_waitcnt vmcnt(0)" ::: "memory");
    __syncthreads();

    const int rm = (row >> 1) & 7;                   // == (s>>3)&7 for our read slots

    for (int kt = 0; kt < 32; ++kt) {
        const int cur = kt & 1;
        if (kt + 1 < 32) STAGE(cur ^ 1, kt + 1);

        bf16x8 a[4], b[4];
#pragma unroll
        for (int i = 0; i < 4; ++i) {
            const int s = ((wr * 64 + 16 * i + row) * 4 + quad) ^ rm;
            a[i] = ld8(BPc(&lA[cur][(size_t)s * 8]));
        }
#pragma unroll
        for (int j = 0; j < 4; ++j) {
            const int s = ((wc * 64 + 16 * j + row) * 4 + quad) ^ rm;
            b[j] = ld8(BPc(&lB[cur][(size_t)s * 8]));
        }
#pragma unroll
        for (int i = 0; i < 4; ++i)
#pragma unroll
            for (int j = 0; j < 4; ++j)
                acc[i][j] = MF(a[i], b[j], acc[i][j]);

        asm volatile("s_waitcnt vmcnt(0)" ::: "memory");
        __syncthreads();
    }

#pragma unroll
    for (int i = 0; i < 4; ++i)
#pragma unroll
        for (int j = 0; j < 4; ++j) {
            const int n = n_base + wc * 64 + 16 * j + row;
#pragma unroll
            for (int r = 0; r < 4; ++r) {
                const int m = m_base + wr * 64 + 16 * i + quad * 4 + r;
                float v = acc[i][j][r] + g_featb[(size_t)(m & 255) * G4 + n];
                BP(g_xg)[(size_t)m * G4 + n] = __float2bfloat16(v);
            }
        }
}

// =============================================================
// Persistent LSTM chunk: 16 timesteps in ONE plain launch.
// Grid 128 blocks x 512 thr; LDS 144 KB -> 1 block/CU; 128 blocks <= 256 CUs
// so all blocks dispatch immediately (no stranding -> spin barrier safe).
// Block (jg,bh): j-cols [jg*16,+16), batches [bh*128,+128).
// Whh slice (4 gates x 16 cols x 1024 K = 128 KB) loaded ONCE, fragment-
// ordered: granule G = g*2048+kt*64+l holds Whh[g*1024+j0+(l&15)]
// [kt*32+(l>>4)*8..+8] -> ds_read = base + lane*16 + imm: conflict-free.
// Wave wv (0..7) owns batch rows bh*128+wv*16..+16; per kt: 1 A-frag from
// global h (no cross-wave redundancy) + 4 B-frags from LDS + 4 MFMA.
// Gate exchange via gsum[64][65] in two 64-batch halves; elementwise
// update; device barrier (release fence -> atomic arrive -> acquire fence)
// between steps. Monotonic epoch, base re-read per launch (replay-safe).
// =============================================================
__global__ __launch_bounds__(512, 1) void lstm_chunk(
    const int* __restrict__ length,
    float* __restrict__ out,          // (T,B,H) f32 base (layer-1 writes)
    int c0, int layer)
{
    __shared__ unsigned short WL[64 * 1024];   // 128 KB fragment-ordered Whh
    __shared__ float gsum[64][65];             // 16.6 KB padded exchange
    __shared__ unsigned s_base;

    const int tid  = threadIdx.x;
    const int lane = tid & 63, wv = tid >> 6;
    const int row  = lane & 15, quad = lane >> 4;
    const int jg = blockIdx.x >> 1, bh = blockIdx.x & 1;
    const int j0 = jg * 16;
    const int bb0 = bh * 128;

    if (tid == 0)
        s_base = __hip_atomic_load(&g_bar_epoch, __ATOMIC_RELAXED,
                                   __HIP_MEMORY_SCOPE_AGENT);

    {   // ---- load Whh slice, fragment-ordered (once per chunk) ----
        const __hip_bfloat16* Whh = BPc(g_Whh) + (size_t)layer * G4 * 1024;
#pragma unroll
        for (int i = 0; i < 16; ++i) {
            const int G = tid + i * 512;                 // 0..8191 granules
            const int g = G >> 11, kt = (G >> 6) & 31, l = G & 63;
            *reinterpret_cast<bf16x8*>(&WL[(size_t)G * 8]) =
                ld8(Whh + (size_t)(g * 1024 + j0 + (l & 15)) * 1024
                        + kt * 32 + (l >> 4) * 8);
        }
    }
    __syncthreads();
    const unsigned base = s_base;

    for (int s = 0; s < CHT; ++s) {
        const int t = c0 + s;
        const __hip_bfloat16* h_in = (t > 0) ? BPc(g_h[(t + 1) & 1]) : nullptr;
        __hip_bfloat16* h_out = BP(g_h[t & 1]);
        const __hip_bfloat16* xg = BPc(g_xg) + (size_t)s * BB * G4;

        f32x4 acc[4] = {};          // 4 gates, one 16x16 frag (rows = batches)
        if (h_in) {
            const __hip_bfloat16* ap =
                h_in + (size_t)(bb0 + wv * 16 + row) * HH + quad * 8;
            const unsigned short* wl = &WL[(size_t)lane * 8];
#pragma unroll 8
            for (int kt = 0; kt < 32; ++kt) {
                bf16x8 af = ld8(ap + kt * 32);
                acc[0] = MF(af, *(const bf16x8*)(wl + (size_t)(0 * 16384 + kt * 512)), acc[0]);
                acc[1] = MF(af, *(const bf16x8*)(wl + (size_t)(1 * 16384 + kt * 512)), acc[1]);
                acc[2] = MF(af, *(const bf16x8*)(wl + (size_t)(2 * 16384 + kt * 512)), acc[2]);
                acc[3] = MF(af, *(const bf16x8*)(wl + (size_t)(3 * 16384 + kt * 512)), acc[3]);
            }
        }

        // ---- exchange + elementwise update, two 64-batch halves ----
#pragma unroll
        for (int half = 0; half < 2; ++half) {
            if ((wv >> 2) == half) {
#pragma unroll
                for (int g = 0; g < 4; ++g)
#pragma unroll
                    for (int r = 0; r < 4; ++r)
                        gsum[(wv & 3) * 16 + quad * 4 + r][g * 16 + row] = acc[g][r];
            }
            __syncthreads();
            const int b0 = bb0 + half * 64;
            for (int e = tid; e < 1024; e += 512) {
                const int lb = e >> 4, lj = e & 15;
                const int b = b0 + lb, j = j0 + lj;
                const size_t xb = (size_t)b * G4 + j;
                const float gi = gsum[lb][ 0 + lj] + (float)xg[xb];
                const float gf = gsum[lb][16 + lj] + (float)xg[xb + HH];
                const float gg = gsum[lb][32 + lj] + (float)xg[xb + 2 * HH];
                const float go = gsum[lb][48 + lj] + (float)xg[xb + 3 * HH];
                const size_t idx = (size_t)b * HH + j;
                float hv;
                if (t < length[b]) {
                    const float c_old = g_c[idx];
                    const float si = 1.0f / (1.0f + __expf(-gi));
                    const float sf = 1.0f / (1.0f + __expf(-gf));
                    const float so = 1.0f / (1.0f + __expf(-go));
                    const float c_new = sf * c_old + si * tanhf(gg);
                    g_c[idx] = c_new;
                    hv = so * tanhf(c_new);
                } else {
                    hv = h_in ? (float)h_in[idx] : 0.0f;   // frozen past seq end
                }
                const __hip_bfloat16 hb = __float2bfloat16(hv);
                h_out[idx] = hb;
                if (layer == 0) BP(g_seq)[(size_t)t * BB * HH + idx] = hb;
                else            out[(size_t)t * BB * HH + idx] = hv;
            }
            __syncthreads();
        }

        // ---- device-wide barrier between steps (not after the last) ----
        if (s + 1 < CHT) {
            if (tid == 0) {
                __threadfence();                               // release our writes
                if (atomicAdd(&g_bar_cnt, 1u) == NBLK_LSTM - 1u) {
                    __hip_atomic_store(&g_bar_cnt, 0u, __ATOMIC_RELAXED,
                                       __HIP_MEMORY_SCOPE_AGENT);
                    __threadfence();
                    atomicAdd(&g_bar_epoch, 1u);               // release epoch
                } else {
                    const unsigned want = base + (unsigned)s + 1u;
                    while (__hip_atomic_load(&g_bar_epoch, __ATOMIC_RELAXED,
                                             __HIP_MEMORY_SCOPE_AGENT) < want)
                        __builtin_amdgcn_s_sleep(2);
                }
                __threadfence();                               // acquire side
            }
            __syncthreads();
        }
    }
}

// ---------------- small utility kernels ----------------
__global__ __launch_bounds__(256) void zero_c() {
    g_c[blockIdx.x * 256 + threadIdx.x] = 0.0f;
}
__global__ __launch_bounds__(256) void finish_layer(float* __restrict__ hn,
                                                    float* __restrict__ cn)
{
    const int i = blockIdx.x * 256 + threadIdx.x;
    hn[i] = (float)BPc(g_h[(TT - 1) & 1])[i];
    cn[i] = g_c[i];
}

// =============================================================
// host launcher — plain kernel launches ONLY (graph-capture safe)
// =============================================================
extern "C" void kernel_launch(void* const* d_in, const int* in_sizes, int n_in,
                              void* d_out, int out_size, void* d_ws, size_t ws_size,
                              hipStream_t stream)
{
    const float* x        = (const float*)d_in[0];  // (T,B,D)   f32
    const float* features = (const float*)d_in[1];  // (B,F)     f32
    const float* Wih      = (const float*)d_in[2];  // (L,4H,D)  f32
    const float* Whh      = (const float*)d_in[3];  // (L,4H,H)  f32
    const float* Wfh      = (const float*)d_in[4];  // (L,4H,F)  f32
    const float* bvec     = (const float*)d_in[5];  // (L,4H)    f32
    const int*   length   = (const int*)d_in[6];    // (B,)
    float* out = (float*)d_out;                     // f32 outputs

    const size_t nX = (size_t)TT * BB * DD;
    const size_t nW = (size_t)2 * G4 * 1024;
    const size_t nF = (size_t)BB * 1024;
    cvt_bf16<<<(int)(nX / 1024), 256, 0, stream>>>(0, x, nX);
    cvt_bf16<<<(int)(nW / 1024), 256, 0, stream>>>(1, Wih, nW);
    cvt_bf16<<<(int)(nW / 1024), 256, 0, stream>>>(2, Whh, nW);
    cvt_bf16<<<(int)(nW / 1024), 256, 0, stream>>>(3, Wfh, nW);
    cvt_bf16<<<(int)(nF / 1024), 256, 0, stream>>>(4, features, nF);

    float* out_hn = out + (size_t)TT * BB * HH;
    float* out_cn = out_hn + (size_t)2 * BB * HH;

    for (int l = 0; l < 2; ++l) {
        const size_t w_off = (size_t)l * G4 * 1024;

        gemm_featb<<<dim3(G4 / 64, BB / 128), 256, 0, stream>>>(
            w_off, bvec + (size_t)l * G4);
        zero_c<<<BB * HH / 256, 256, 0, stream>>>();

        for (int c0 = 0; c0 < TT; c0 += CHT) {
            // g_xg = g_seq[chunk] @ Wih[l]^T + g_featb   (bf16 [CHT*B,4H])
            gemm_xg<<<dim3(G4 / 128, CHT * BB / 128), 256, 0, stream>>>(
                (size_t)c0 * BB * DD, w_off);

            // 16 recurrent steps, one persistent launch with in-kernel barriers
            lstm_chunk<<<NBLK_LSTM, 512, 0, stream>>>(length, out, c0, l);
        }

        finish_layer<<<BB * HH / 256, 256, 0, stream>>>(
            out_hn + (size_t)l * BB * HH, out_cn + (size_t)l * BB * HH);
    }
}

// Round 4
// 3140.859 us; speedup vs baseline: 1.1304x; 1.1304x over previous
//
#include <hip/hip_runtime.h>
#include <hip/hip_bf16.h>

// ---------------- problem shape ----------------
#define TT 64
#define BB 256
#define DD 1024
#define HH 1024
#define G4 4096    // 4*H
#define CHT 16     // xg chunk length (timesteps); 4 chunks cover T=64
#define NBLK_LSTM 128

typedef __bf16 bf16x8 __attribute__((ext_vector_type(8)));
typedef float  f32x4  __attribute__((ext_vector_type(4)));

// ---------------- static device scratch (~119 MB, Round-1-proven size) ----------------
__device__ unsigned short g_seq [(size_t)TT * BB * 1024];  // x (bf16) -> layer-1 h seq   32 MB
__device__ unsigned short g_Wih [(size_t)2 * G4 * 1024];   // 16 MB
__device__ unsigned short g_Whh [(size_t)2 * G4 * 1024];   // 16 MB
__device__ unsigned short g_Wfh [(size_t)2 * G4 * 1024];   // 16 MB
__device__ unsigned short g_feat[(size_t)BB * 1024];       // 0.5 MB
__device__ unsigned short g_xg  [(size_t)CHT * BB * G4];   // bf16 gates chunk            32 MB
__device__ unsigned short g_h   [2][(size_t)BB * HH];      // h state ping-pong (bf16)     1 MB
__device__ float          g_featb[(size_t)BB * G4];        // f32 feat@Wfh^T + b           4 MB
__device__ float          g_c   [(size_t)BB * HH];         // f32 cell state               1 MB

// distributed barrier flags: [bh group][jg block][64B pad]. Monotonic epochs
// (never reset -> graph-replay safe). Each block's flag on its own cacheline
// -> arrivals are parallel stores, no serialized central atomic.
__device__ unsigned g_arrive[2][64][16];

__device__ __forceinline__ bf16x8 ld8(const __hip_bfloat16* p) {
    return *reinterpret_cast<const bf16x8*>(p);
}
__device__ __forceinline__ __hip_bfloat16* BP(unsigned short* p) {
    return reinterpret_cast<__hip_bfloat16*>(p);
}
__device__ __forceinline__ const __hip_bfloat16* BPc(const unsigned short* p) {
    return reinterpret_cast<const __hip_bfloat16*>(p);
}
__device__ __forceinline__ f32x4 MF(bf16x8 a, bf16x8 b, f32x4 c) {
    return __builtin_amdgcn_mfma_f32_16x16x32_bf16(a, b, c, 0, 0, 0);
}

// direct global->LDS async copy, 16B per lane
typedef unsigned int u32_g __attribute__((address_space(1)));
typedef unsigned int u32_l __attribute__((address_space(3)));
__device__ __forceinline__ void gload16(const void* g, void* l) {
    __builtin_amdgcn_global_load_lds((const u32_g*)g, (u32_l*)l, 16, 0, 0);
}

// =============================================================
// f32 -> bf16 conversion into a selected device-global buffer.
// =============================================================
__global__ __launch_bounds__(256) void cvt_bf16(int which,
                                                const float* __restrict__ s,
                                                size_t n)
{
    size_t i = ((size_t)blockIdx.x * 256 + threadIdx.x) * 4;
    if (i >= n) return;
    unsigned short* d = (which == 0) ? g_seq
                      : (which == 1) ? g_Wih
                      : (which == 2) ? g_Whh
                      : (which == 3) ? g_Wfh : g_feat;
    float4 v = *reinterpret_cast<const float4*>(s + i);
    __hip_bfloat16* db = BP(d) + i;
    db[0] = __float2bfloat16(v.x);
    db[1] = __float2bfloat16(v.y);
    db[2] = __float2bfloat16(v.z);
    db[3] = __float2bfloat16(v.w);
}

// =============================================================
// Small-M featb GEMM: g_featb[256,4096] = feat @ Wfh[l]^T + b[l] (f32)
// =============================================================
__global__ __launch_bounds__(256) void gemm_featb(size_t w_off,
                                                  const float* __restrict__ bias)
{
    const int tid  = threadIdx.x;
    const int lane = tid & 63, wid = tid >> 6;
    const int row  = lane & 15, quad = lane >> 4;
    const int m_base = blockIdx.y * 128 + (wid >> 1) * 64;
    const int n_base = blockIdx.x * 64  + (wid & 1) * 32;

    const __hip_bfloat16* A = BPc(g_feat);
    const __hip_bfloat16* W = BPc(g_Wfh) + w_off;

    f32x4 acc[4][2] = {};
    const __hip_bfloat16* Ap = A + (size_t)(m_base + row) * 1024 + quad * 8;
    const __hip_bfloat16* Wp = W + (size_t)(n_base + row) * 1024 + quad * 8;

    for (int k0 = 0; k0 < 1024; k0 += 32) {
        bf16x8 a[4], b[2];
#pragma unroll
        for (int i = 0; i < 4; ++i) a[i] = ld8(Ap + (size_t)(16 * i) * 1024 + k0);
#pragma unroll
        for (int j = 0; j < 2; ++j) b[j] = ld8(Wp + (size_t)(16 * j) * 1024 + k0);
#pragma unroll
        for (int i = 0; i < 4; ++i)
#pragma unroll
            for (int j = 0; j < 2; ++j)
                acc[i][j] = MF(a[i], b[j], acc[i][j]);
    }
#pragma unroll
    for (int i = 0; i < 4; ++i)
#pragma unroll
        for (int j = 0; j < 2; ++j) {
            const int n = n_base + 16 * j + row;
#pragma unroll
            for (int r = 0; r < 4; ++r) {
                const int m = m_base + 16 * i + quad * 4 + r;
                g_featb[(size_t)m * G4 + n] = acc[i][j][r] + bias[n];
            }
        }
}

// =============================================================
// xg GEMM (chunk): C[4096,4096] = g_seq[chunk] @ Wih[l]^T  (+featb, ->bf16)
// 128x128 tile, BK=32, double-buffered LDS via global_load_lds(16B).
// Bank-conflict fix (rule #21, both-sides involution): LDS dest LINEAR,
// global source pre-permuted by s' = s ^ ((s>>3)&7) on 16B-granules,
// ds_read applies the same involution.
// =============================================================
__global__ __launch_bounds__(256) void gemm_xg(size_t seq_off, size_t w_off)
{
    __shared__ unsigned short lA[2][128 * 32];
    __shared__ unsigned short lB[2][128 * 32];

    const int tid  = threadIdx.x;
    const int lane = tid & 63, wv = tid >> 6;
    const int row  = lane & 15, quad = lane >> 4;
    const int wr = wv >> 1, wc = wv & 1;
    const int m_base = blockIdx.y * 128;
    const int n_base = blockIdx.x * 128;

    const __hip_bfloat16* A  = BPc(g_seq) + seq_off + (size_t)m_base * 1024;
    const __hip_bfloat16* Wt = BPc(g_Wih) + w_off   + (size_t)n_base * 1024;

    f32x4 acc[4][4] = {};

    const int sm = (tid >> 3) & 7;                   // == (d>>3)&7 for d=it*256+tid
    auto STAGE = [&](int bf, int kt) {
        const int k0 = kt * 32;
#pragma unroll
        for (int it = 0; it < 2; ++it) {
            const int d = it * 256 + tid;
            const int l = d ^ sm;                    // involutive granule permutation
            const int r  = l >> 2;
            const int kc = k0 + (l & 3) * 8;
            unsigned short* dA = &lA[bf][(size_t)(it * 256 + wv * 64) * 8];
            unsigned short* dB = &lB[bf][(size_t)(it * 256 + wv * 64) * 8];
            gload16(A  + (size_t)r * 1024 + kc, dA);
            gload16(Wt + (size_t)r * 1024 + kc, dB);
        }
    };

    STAGE(0, 0);
    asm volatile("s_waitcnt vmcnt(0)" ::: "memory");
    __syncthreads();

    const int rm = (row >> 1) & 7;                   // == (s>>3)&7 for our read slots

    for (int kt = 0; kt < 32; ++kt) {
        const int cur = kt & 1;
        if (kt + 1 < 32) STAGE(cur ^ 1, kt + 1);

        bf16x8 a[4], b[4];
#pragma unroll
        for (int i = 0; i < 4; ++i) {
            const int s = ((wr * 64 + 16 * i + row) * 4 + quad) ^ rm;
            a[i] = ld8(BPc(&lA[cur][(size_t)s * 8]));
        }
#pragma unroll
        for (int j = 0; j < 4; ++j) {
            const int s = ((wc * 64 + 16 * j + row) * 4 + quad) ^ rm;
            b[j] = ld8(BPc(&lB[cur][(size_t)s * 8]));
        }
#pragma unroll
        for (int i = 0; i < 4; ++i)
#pragma unroll
            for (int j = 0; j < 4; ++j)
                acc[i][j] = MF(a[i], b[j], acc[i][j]);

        asm volatile("s_waitcnt vmcnt(0)" ::: "memory");
        __syncthreads();
    }

#pragma unroll
    for (int i = 0; i < 4; ++i)
#pragma unroll
        for (int j = 0; j < 4; ++j) {
            const int n = n_base + wc * 64 + 16 * j + row;
#pragma unroll
            for (int r = 0; r < 4; ++r) {
                const int m = m_base + wr * 64 + 16 * i + quad * 4 + r;
                float v = acc[i][j][r] + g_featb[(size_t)(m & 255) * G4 + n];
                BP(g_xg)[(size_t)m * G4 + n] = __float2bfloat16(v);
            }
        }
}

// =============================================================
// Persistent LSTM chunk: 16 timesteps in ONE launch.
// Grid 128 blocks x 512 thr; LDS ~145 KB -> 1 block/CU; all blocks resident.
// Block (jg,bh): j-cols [jg*16,+16), batches [bh*128,+128).
// KEY (R4): the recurrence only couples blocks sharing batches -> barrier is
// per-bh GROUP (64 blocks), implemented as distributed arrive-flags:
//   arrive: __threadfence (release) + store own padded flag (parallel, no
//           central atomic serialization — R3's atomicAdd chain cost ~21us/step)
//   wait:   wave 0 polls all 64 group flags, one per lane, until
//           __all(flag >= want); __threadfence (acquire); __syncthreads.
// Flags are monotone; base re-read from own flag each launch (replay-safe).
// =============================================================
__global__ __launch_bounds__(512, 1) void lstm_chunk(
    const int* __restrict__ length,
    float* __restrict__ out,          // (T,B,H) f32 base (layer-1 writes)
    int c0, int layer)
{
    __shared__ unsigned short WL[64 * 1024];   // 128 KB fragment-ordered Whh
    __shared__ float gsum[64][65];             // 16.6 KB padded exchange
    __shared__ int   slen[128];                // lengths for this block's batches
    __shared__ unsigned s_base;

    const int tid  = threadIdx.x;
    const int lane = tid & 63, wv = tid >> 6;
    const int row  = lane & 15, quad = lane >> 4;
    const int jg = blockIdx.x >> 1, bh = blockIdx.x & 1;
    const int j0 = jg * 16;
    const int bb0 = bh * 128;

    if (tid == 0)
        s_base = __hip_atomic_load(&g_arrive[bh][jg][0], __ATOMIC_RELAXED,
                                   __HIP_MEMORY_SCOPE_AGENT);
    if (tid < 128) slen[tid] = length[bb0 + tid];

    {   // ---- load Whh slice, fragment-ordered (once per chunk) ----
        const __hip_bfloat16* Whh = BPc(g_Whh) + (size_t)layer * G4 * 1024;
#pragma unroll
        for (int i = 0; i < 16; ++i) {
            const int G = tid + i * 512;                 // 0..8191 granules
            const int g = G >> 11, kt = (G >> 6) & 31, l = G & 63;
            *reinterpret_cast<bf16x8*>(&WL[(size_t)G * 8]) =
                ld8(Whh + (size_t)(g * 1024 + j0 + (l & 15)) * 1024
                        + kt * 32 + (l >> 4) * 8);
        }
    }
    __syncthreads();
    const unsigned base = s_base;

    for (int s = 0; s < CHT; ++s) {
        const int t = c0 + s;
        const __hip_bfloat16* h_in = (t > 0) ? BPc(g_h[(t + 1) & 1]) : nullptr;
        __hip_bfloat16* h_out = BP(g_h[t & 1]);
        const __hip_bfloat16* xg = BPc(g_xg) + (size_t)s * BB * G4;

        f32x4 acc[4] = {};          // 4 gates, one 16x16 frag (rows = batches)
        if (h_in) {
            const __hip_bfloat16* ap =
                h_in + (size_t)(bb0 + wv * 16 + row) * HH + quad * 8;
            const unsigned short* wl = &WL[(size_t)lane * 8];
#pragma unroll 8
            for (int kt = 0; kt < 32; ++kt) {
                bf16x8 af = ld8(ap + kt * 32);
                acc[0] = MF(af, *(const bf16x8*)(wl + (size_t)(0 * 16384 + kt * 512)), acc[0]);
                acc[1] = MF(af, *(const bf16x8*)(wl + (size_t)(1 * 16384 + kt * 512)), acc[1]);
                acc[2] = MF(af, *(const bf16x8*)(wl + (size_t)(2 * 16384 + kt * 512)), acc[2]);
                acc[3] = MF(af, *(const bf16x8*)(wl + (size_t)(3 * 16384 + kt * 512)), acc[3]);
            }
        }

        // ---- exchange + elementwise update, two 64-batch halves ----
#pragma unroll
        for (int half = 0; half < 2; ++half) {
            if ((wv >> 2) == half) {
#pragma unroll
                for (int g = 0; g < 4; ++g)
#pragma unroll
                    for (int r = 0; r < 4; ++r)
                        gsum[(wv & 3) * 16 + quad * 4 + r][g * 16 + row] = acc[g][r];
            }
            __syncthreads();
            const int b0 = bb0 + half * 64;
            for (int e = tid; e < 1024; e += 512) {
                const int lb = e >> 4, lj = e & 15;
                const int b = b0 + lb, j = j0 + lj;
                const size_t xb = (size_t)b * G4 + j;
                const float gi = gsum[lb][ 0 + lj] + (float)xg[xb];
                const float gf = gsum[lb][16 + lj] + (float)xg[xb + HH];
                const float gg = gsum[lb][32 + lj] + (float)xg[xb + 2 * HH];
                const float go = gsum[lb][48 + lj] + (float)xg[xb + 3 * HH];
                const size_t idx = (size_t)b * HH + j;
                float hv;
                if (t < slen[half * 64 + lb]) {
                    const float c_old = g_c[idx];
                    const float si = 1.0f / (1.0f + __expf(-gi));
                    const float sf = 1.0f / (1.0f + __expf(-gf));
                    const float so = 1.0f / (1.0f + __expf(-go));
                    const float c_new = sf * c_old + si * tanhf(gg);
                    g_c[idx] = c_new;
                    hv = so * tanhf(c_new);
                } else {
                    hv = h_in ? (float)h_in[idx] : 0.0f;   // frozen past seq end
                }
                const __hip_bfloat16 hb = __float2bfloat16(hv);
                h_out[idx] = hb;
                if (layer == 0) BP(g_seq)[(size_t)t * BB * HH + idx] = hb;
                else            out[(size_t)t * BB * HH + idx] = hv;
            }
            __syncthreads();
        }

        // ---- distributed group barrier between steps (not after the last) ----
        if (s + 1 < CHT) {
            const unsigned want = base + (unsigned)s + 1u;
            if (tid == 0) {
                __threadfence();                           // release this step's writes
                __hip_atomic_store(&g_arrive[bh][jg][0], want,
                                   __ATOMIC_RELAXED, __HIP_MEMORY_SCOPE_AGENT);
            }
            if (wv == 0) {                                 // lane l watches block l
                unsigned v;
                do {
                    v = __hip_atomic_load(&g_arrive[bh][lane][0],
                                          __ATOMIC_RELAXED, __HIP_MEMORY_SCOPE_AGENT);
                    if (v < want) __builtin_amdgcn_s_sleep(2);
                } while (__any(v < want));
                __threadfence();                           // acquire side
            }
            __syncthreads();
        }
    }
}

// ---------------- small utility kernels ----------------
__global__ __launch_bounds__(256) void zero_c() {
    g_c[blockIdx.x * 256 + threadIdx.x] = 0.0f;
}
__global__ __launch_bounds__(256) void finish_layer(float* __restrict__ hn,
                                                    float* __restrict__ cn)
{
    const int i = blockIdx.x * 256 + threadIdx.x;
    hn[i] = (float)BPc(g_h[(TT - 1) & 1])[i];
    cn[i] = g_c[i];
}

// =============================================================
// host launcher — plain kernel launches ONLY (graph-capture safe)
// =============================================================
extern "C" void kernel_launch(void* const* d_in, const int* in_sizes, int n_in,
                              void* d_out, int out_size, void* d_ws, size_t ws_size,
                              hipStream_t stream)
{
    const float* x        = (const float*)d_in[0];  // (T,B,D)   f32
    const float* features = (const float*)d_in[1];  // (B,F)     f32
    const float* Wih      = (const float*)d_in[2];  // (L,4H,D)  f32
    const float* Whh      = (const float*)d_in[3];  // (L,4H,H)  f32
    const float* Wfh      = (const float*)d_in[4];  // (L,4H,F)  f32
    const float* bvec     = (const float*)d_in[5];  // (L,4H)    f32
    const int*   length   = (const int*)d_in[6];    // (B,)
    float* out = (float*)d_out;                     // f32 outputs

    const size_t nX = (size_t)TT * BB * DD;
    const size_t nW = (size_t)2 * G4 * 1024;
    const size_t nF = (size_t)BB * 1024;
    cvt_bf16<<<(int)(nX / 1024), 256, 0, stream>>>(0, x, nX);
    cvt_bf16<<<(int)(nW / 1024), 256, 0, stream>>>(1, Wih, nW);
    cvt_bf16<<<(int)(nW / 1024), 256, 0, stream>>>(2, Whh, nW);
    cvt_bf16<<<(int)(nW / 1024), 256, 0, stream>>>(3, Wfh, nW);
    cvt_bf16<<<(int)(nF / 1024), 256, 0, stream>>>(4, features, nF);

    float* out_hn = out + (size_t)TT * BB * HH;
    float* out_cn = out_hn + (size_t)2 * BB * HH;

    for (int l = 0; l < 2; ++l) {
        const size_t w_off = (size_t)l * G4 * 1024;

        gemm_featb<<<dim3(G4 / 64, BB / 128), 256, 0, stream>>>(
            w_off, bvec + (size_t)l * G4);
        zero_c<<<BB * HH / 256, 256, 0, stream>>>();

        for (int c0 = 0; c0 < TT; c0 += CHT) {
            // g_xg = g_seq[chunk] @ Wih[l]^T + g_featb   (bf16 [CHT*B,4H])
            gemm_xg<<<dim3(G4 / 128, CHT * BB / 128), 256, 0, stream>>>(
                (size_t)c0 * BB * DD, w_off);

            // 16 recurrent steps, one persistent launch with group barriers
            lstm_chunk<<<NBLK_LSTM, 512, 0, stream>>>(length, out, c0, l);
        }

        finish_layer<<<BB * HH / 256, 256, 0, stream>>>(
            out_hn + (size_t)l * BB * HH, out_cn + (size_t)l * BB * HH);
    }
}